// Round 1
// baseline (1171.586 us; speedup 1.0000x reference)
//
#include <hip/hip_runtime.h>
#include <stdint.h>

// QLoRA BigNet forward, MI355X/gfx950.
// Strategy: fold LoRA into dequantized weights (W_eff = dequant + B@A, fp16),
// then 18 GEMMs [16384,1024]x[1024,1024]^T with fused bias/relu/residual
// epilogues + 5 separate LayerNorm kernels. m97-structure GEMM: 128x128 tile,
// BK=64, global_load_lds(16B) staging with XOR-swizzled LDS (pre-swizzled
// global source, swizzled ds_read), 16x16x32 f16 MFMA, XCD-aware block swizzle.
// Activations ping-pong through 3 fp16 buffers; buffer 0 lives in d_out's 64MB
// (dead by the time the final fp32 GEMM overwrites d_out).
// ws requirement: 18MB*2 weights + 2*32MB activations = 100MB.

#define TOK   16384
#define DIM   1024
#define NLIN  18
#define EPS   1e-5f

typedef _Float16 f16;
typedef _Float16 f16x8 __attribute__((ext_vector_type(8)));
typedef _Float16 f16x4 __attribute__((ext_vector_type(4)));
typedef float    f32x4 __attribute__((ext_vector_type(4)));

__device__ __forceinline__ void load_lds16(const void* g, void* l) {
  __builtin_amdgcn_global_load_lds(
      (const __attribute__((address_space(1))) void*)g,
      (__attribute__((address_space(3))) void*)l,
      16, 0, 0);
}

// ---------------------------------------------------------------------------
// prep: W_eff[i][o][k] = (q/15*2-1)*norm[o][k/128] + sum_r lb[o][r]*la[r][k]
// one block per (layer, out-row); 256 threads x 4 k-elements.
// ---------------------------------------------------------------------------
__global__ __launch_bounds__(256) void prep_weights(
    const int* __restrict__ q, const float* __restrict__ norm,
    const float* __restrict__ la, const float* __restrict__ lb,
    f16* __restrict__ W)
{
  const int bid = blockIdx.x;            // i*1024 + o
  const int i = bid >> 10;
  const int k4 = threadIdx.x * 4;
  const int4 qv = *(const int4*)(q + ((size_t)bid << 10) + k4);
  const float nrm = norm[bid * 8 + (k4 >> 7)];
  const float* lbr = lb + (size_t)bid * 32;
  const float* lal = la + (size_t)i * 32 * 1024 + k4;
  float ax = 0.f, ay = 0.f, az = 0.f, aw = 0.f;
  #pragma unroll
  for (int r = 0; r < 32; ++r) {
    const float b = lbr[r];
    const float4 a = *(const float4*)(lal + r * 1024);
    ax += b * a.x; ay += b * a.y; az += b * a.z; aw += b * a.w;
  }
  const float s = 2.f / 15.f;
  f16x4 hv;
  hv[0] = (f16)(((float)qv.x * s - 1.f) * nrm + ax);
  hv[1] = (f16)(((float)qv.y * s - 1.f) * nrm + ay);
  hv[2] = (f16)(((float)qv.z * s - 1.f) * nrm + az);
  hv[3] = (f16)(((float)qv.w * s - 1.f) * nrm + aw);
  *(f16x4*)(W + ((size_t)bid << 10) + k4) = hv;
}

// ---------------------------------------------------------------------------
// x (fp32) -> fp16 activation buffer
// ---------------------------------------------------------------------------
__global__ __launch_bounds__(256) void cvt_x(
    const float* __restrict__ x, f16* __restrict__ o)
{
  const size_t idx = ((size_t)blockIdx.x * 256 + threadIdx.x) * 4;
  const float4 v = *(const float4*)(x + idx);
  f16x4 h;
  h[0] = (f16)v.x; h[1] = (f16)v.y; h[2] = (f16)v.z; h[3] = (f16)v.w;
  *(f16x4*)(o + idx) = h;
}

// ---------------------------------------------------------------------------
// GEMM: out[t][o] = sum_k A[t][k]*W[o][k] + bias[o] (+epilogue)
// EPI 0: relu -> f16   EPI 1: +resid -> f16 (pre-LN)   EPI 2: +resid -> f32
// 128x128 tile, BK=64, 4 waves (2x2), each wave 64x64 via 4x4 16x16x32 frags.
// LDS XOR swizzle: byte ^= (row&7)<<4 within each 128B row; staging loads the
// inverse-permuted global chunk so global_load_lds' linear dest lands right.
// ---------------------------------------------------------------------------
template<int EPI>
__global__ __launch_bounds__(256) void gemm_ql(
    const f16* __restrict__ A, const f16* __restrict__ W,
    const float* __restrict__ bias, const f16* __restrict__ resid,
    void* __restrict__ outp)
{
  __shared__ __align__(16) f16 sA[128 * 64];
  __shared__ __align__(16) f16 sB[128 * 64];

  // XCD-aware swizzle (nwg=1024, 8 XCDs): each XCD gets 16 mtiles x all 8
  // ntiles -> B panel (2MB) + 16 A panels (4MB) live in its L2.
  const int orig = blockIdx.x;
  const int swzb = (orig & 7) * 128 + (orig >> 3);
  const int mt = swzb >> 3, nt = swzb & 7;
  const int t0 = mt * 128, n0 = nt * 128;

  const int tid  = threadIdx.x;
  const int lane = tid & 63;
  const int wid  = tid >> 6;
  const int wm = wid >> 1, wn = wid & 1;

  // staging: chunk = qq*256+tid over 16B chunks; row=chunk>>3, c=chunk&7.
  // row&7 invariant across qq (qq advances rows by 32).
  const int rb = tid >> 3;
  const int gc = (tid & 7) ^ (rb & 7);       // inverse-swizzled global chunk
  const f16* gA = A + (size_t)(t0 + rb) * DIM + gc * 8;
  const f16* gB = W + (size_t)(n0 + rb) * DIM + gc * 8;
  const int ldst = tid * 16;                  // byte dest within 4KB round

  f32x4 acc[4][4] = {};

  // kt-invariant fragment read offsets (swizzled)
  int aoff[2][4], boff[2][4];
  #pragma unroll
  for (int kk = 0; kk < 2; ++kk) {
    const int kbyte = kk * 64 + ((lane >> 4) << 4);
    #pragma unroll
    for (int f = 0; f < 4; ++f) {
      const int ra = wm * 64 + f * 16 + (lane & 15);
      aoff[kk][f] = ra * 128 + (kbyte ^ ((ra & 7) << 4));
      const int rn = wn * 64 + f * 16 + (lane & 15);
      boff[kk][f] = rn * 128 + (kbyte ^ ((rn & 7) << 4));
    }
  }

  for (int kt = 0; kt < DIM / 64; ++kt) {
    const f16* a_src = gA + kt * 64;
    const f16* b_src = gB + kt * 64;
    #pragma unroll
    for (int qq = 0; qq < 4; ++qq) {
      load_lds16(a_src + (size_t)qq * 32 * DIM, (char*)sA + qq * 4096 + ldst);
      load_lds16(b_src + (size_t)qq * 32 * DIM, (char*)sB + qq * 4096 + ldst);
    }
    __syncthreads();   // compiler drains vmcnt before s_barrier
    #pragma unroll
    for (int kk = 0; kk < 2; ++kk) {
      f16x8 af[4], bf[4];
      #pragma unroll
      for (int f = 0; f < 4; ++f)
        af[f] = *(const f16x8*)((const char*)sA + aoff[kk][f]);
      #pragma unroll
      for (int f = 0; f < 4; ++f)
        bf[f] = *(const f16x8*)((const char*)sB + boff[kk][f]);
      #pragma unroll
      for (int mi = 0; mi < 4; ++mi)
        #pragma unroll
        for (int ni = 0; ni < 4; ++ni)
          acc[mi][ni] = __builtin_amdgcn_mfma_f32_16x16x32_f16(
              af[mi], bf[ni], acc[mi][ni], 0, 0, 0);
    }
    __syncthreads();
  }

  // epilogue: C/D layout col=lane&15, row=(lane>>4)*4+r  [m89-verified]
  const int colb = lane & 15;
  const int rowb = (lane >> 4) << 2;
  #pragma unroll
  for (int ni = 0; ni < 4; ++ni) {
    const int col = n0 + wn * 64 + ni * 16 + colb;
    const float bv = bias[col];
    #pragma unroll
    for (int mi = 0; mi < 4; ++mi) {
      const int trow = t0 + wm * 64 + mi * 16 + rowb;
      const f32x4 v = acc[mi][ni];
      #pragma unroll
      for (int r = 0; r < 4; ++r) {
        const size_t idx = (size_t)(trow + r) * DIM + col;
        float val = v[r] + bv;
        if constexpr (EPI == 0) {
          val = fmaxf(val, 0.f);
          ((f16*)outp)[idx] = (f16)val;
        } else if constexpr (EPI == 1) {
          val += (float)resid[idx];
          ((f16*)outp)[idx] = (f16)val;
        } else {
          val += (float)resid[idx];
          ((float*)outp)[idx] = val;
        }
      }
    }
  }
}

// ---------------------------------------------------------------------------
// LayerNorm over DIM=1024, one block per row, in-place safe.
// ---------------------------------------------------------------------------
__global__ __launch_bounds__(256) void ln_k(
    const f16* __restrict__ in, f16* __restrict__ out,
    const float* __restrict__ g, const float* __restrict__ b)
{
  __shared__ float red[8];
  const int row = blockIdx.x;
  const int tid = threadIdx.x;
  const int c = tid * 4;
  const f16x4 v4 = *(const f16x4*)(in + (size_t)row * DIM + c);
  const float v0 = v4[0], v1 = v4[1], v2 = v4[2], v3 = v4[3];
  float s  = v0 + v1 + v2 + v3;
  float s2 = v0 * v0 + v1 * v1 + v2 * v2 + v3 * v3;
  #pragma unroll
  for (int off = 32; off; off >>= 1) {
    s  += __shfl_xor(s,  off);
    s2 += __shfl_xor(s2, off);
  }
  if ((tid & 63) == 0) { red[(tid >> 6) * 2] = s; red[(tid >> 6) * 2 + 1] = s2; }
  __syncthreads();
  s  = red[0] + red[2] + red[4] + red[6];
  s2 = red[1] + red[3] + red[5] + red[7];
  const float mu  = s * (1.f / DIM);
  const float var = fmaxf(s2 * (1.f / DIM) - mu * mu, 0.f);
  const float rs  = rsqrtf(var + EPS);
  const float4 gv = *(const float4*)(g + c);
  const float4 bv = *(const float4*)(b + c);
  f16x4 o4;
  o4[0] = (f16)((v0 - mu) * rs * gv.x + bv.x);
  o4[1] = (f16)((v1 - mu) * rs * gv.y + bv.y);
  o4[2] = (f16)((v2 - mu) * rs * gv.z + bv.z);
  o4[3] = (f16)((v3 - mu) * rs * gv.w + bv.w);
  *(f16x4*)(out + (size_t)row * DIM + c) = o4;
}

// ---------------------------------------------------------------------------
extern "C" void kernel_launch(void* const* d_in, const int* in_sizes, int n_in,
                              void* d_out, int out_size, void* d_ws, size_t ws_size,
                              hipStream_t stream)
{
  (void)in_sizes; (void)n_in; (void)out_size; (void)ws_size;
  const float* x     = (const float*)d_in[0];
  const int*   q     = (const int*)d_in[1];
  const float* norm  = (const float*)d_in[2];
  const float* bias  = (const float*)d_in[3];
  const float* la    = (const float*)d_in[4];
  const float* lb    = (const float*)d_in[5];
  const float* lg    = (const float*)d_in[6];
  const float* lbeta = (const float*)d_in[7];

  char* ws = (char*)d_ws;
  f16* W    = (f16*)ws;                                   // 36 MB
  f16* buf1 = (f16*)(ws + (size_t)NLIN * DIM * DIM * 2);  // 32 MB
  f16* buf2 = buf1 + (size_t)TOK * DIM;                   // 32 MB
  f16* buf0 = (f16*)d_out;  // scratch inside the 64MB output; dead at final GEMM
  f16* bufs[3] = {buf0, buf1, buf2};

  prep_weights<<<NLIN * DIM, 256, 0, stream>>>(q, norm, la, lb, W);
  cvt_x<<<TOK * DIM / 1024, 256, 0, stream>>>(x, buf0);

  int h = 0;
  for (int blk = 0; blk < 6; ++blk) {
    const int a = (h == 0) ? 1 : 0;
    const int p = 3 - h - a;               // the third buffer
    const int i0 = blk * 3;
    const size_t wsz = (size_t)DIM * DIM;
    gemm_ql<0><<<1024, 256, 0, stream>>>(bufs[h], W + (i0 + 0) * wsz,
                                         bias + (i0 + 0) * DIM, nullptr, bufs[a]);
    gemm_ql<0><<<1024, 256, 0, stream>>>(bufs[a], W + (i0 + 1) * wsz,
                                         bias + (i0 + 1) * DIM, nullptr, bufs[p]);
    if (blk < 5) {
      gemm_ql<1><<<1024, 256, 0, stream>>>(bufs[p], W + (i0 + 2) * wsz,
                                           bias + (i0 + 2) * DIM, bufs[h], bufs[a]);
      ln_k<<<TOK, 256, 0, stream>>>(bufs[a], bufs[a], lg + blk * DIM, lbeta + blk * DIM);
      h = a;
    } else {
      // h==1, p==2 here: final GEMM reads ws buffers only, writes fp32 d_out.
      gemm_ql<2><<<1024, 256, 0, stream>>>(bufs[p], W + (i0 + 2) * wsz,
                                           bias + (i0 + 2) * DIM, bufs[h], d_out);
    }
  }
}

// Round 4
// 1045.012 us; speedup vs baseline: 1.1211x; 1.1211x over previous
//
#include <hip/hip_runtime.h>
#include <stdint.h>

// QLoRA BigNet forward, MI355X/gfx950.  R2 design (3rd submit; R2/R3 were infra
// failures, never ran).
// prep v2: o-tiled lora fold, la in registers (kills 2.3GB redundant L2 reads).
// GEMM v2: 256x256 tile, BK=32, 4x32KB LDS K-tile buffers, 3-deep counted-vmcnt
// pipeline (vmcnt(8) steady state, never drained), 1 barrier/K-tile, setprio
// around MFMA cluster, XOR swizzle (chunk ^= (row>>1)&3 on 64B rows) applied
// involutively on the global source so global_load_lds dest stays linear.
// Grid 256 blocks = 1/CU exactly, 8 waves, 2 waves/SIMD.

#define TOK   16384
#define DIM   1024
#define NLIN  18
#define EPS   1e-5f

typedef _Float16 f16;
typedef _Float16 f16x8 __attribute__((ext_vector_type(8)));
typedef _Float16 f16x4 __attribute__((ext_vector_type(4)));
typedef float    f32x4 __attribute__((ext_vector_type(4)));

__device__ __forceinline__ void load_lds16(const void* g, void* l) {
  __builtin_amdgcn_global_load_lds(
      (const __attribute__((address_space(1))) void*)g,
      (__attribute__((address_space(3))) void*)l,
      16, 0, 0);
}

// ---------------------------------------------------------------------------
// prep v2: W_eff[i][o][k] = dequant + lora.  Block = (i, 128 o-rows, 256 k).
// grid = 18*8*4 = 576.  la[32][k4] cached in registers; lb tile in LDS
// (wave-broadcast reads).  q reads/W writes coalesced & read-once.
// ---------------------------------------------------------------------------
__global__ __launch_bounds__(256) void prep_w2(
    const int* __restrict__ q, const float* __restrict__ norm,
    const float* __restrict__ la, const float* __restrict__ lb,
    f16* __restrict__ W)
{
  __shared__ float lbs[128 * 32];
  const int bid   = blockIdx.x;
  const int i     = bid >> 5;
  const int ot    = (bid >> 2) & 7;
  const int ktile = bid & 3;
  const int o0 = ot * 128, k0 = ktile * 256;
  const int tid = threadIdx.x;
  const int kg = tid & 63, og = tid >> 6;     // og == wave id
  const int k4 = k0 + kg * 4;

  const float* lbsrc = lb + (size_t)i * DIM * 32 + (size_t)o0 * 32;
  #pragma unroll
  for (int p = 0; p < 4; ++p)
    *(float4*)(lbs + p * 1024 + tid * 4) = *(const float4*)(lbsrc + p * 1024 + tid * 4);

  float4 lar[32];
  const float* lasrc = la + (size_t)i * 32 * DIM + k4;
  #pragma unroll
  for (int r = 0; r < 32; ++r) lar[r] = *(const float4*)(lasrc + r * DIM);
  __syncthreads();

  const float s = 2.f / 15.f;
  for (int oi = 0; oi < 32; ++oi) {
    const int o = o0 + og * 32 + oi;
    const size_t wb = ((size_t)i * DIM + o) * DIM;
    const int4 qv = *(const int4*)(q + wb + k4);
    const float nrm = norm[((size_t)i * DIM + o) * 8 + (k4 >> 7)];
    const float* lbr = lbs + (og * 32 + oi) * 32;   // same addr across wave -> broadcast
    float ax = 0.f, ay = 0.f, az = 0.f, aw = 0.f;
    #pragma unroll
    for (int r = 0; r < 32; ++r) {
      const float b = lbr[r];
      ax += b * lar[r].x; ay += b * lar[r].y; az += b * lar[r].z; aw += b * lar[r].w;
    }
    f16x4 hv;
    hv[0] = (f16)(((float)qv.x * s - 1.f) * nrm + ax);
    hv[1] = (f16)(((float)qv.y * s - 1.f) * nrm + ay);
    hv[2] = (f16)(((float)qv.z * s - 1.f) * nrm + az);
    hv[3] = (f16)(((float)qv.w * s - 1.f) * nrm + aw);
    *(f16x4*)(W + wb + k4) = hv;
  }
}

// ---------------------------------------------------------------------------
// x (fp32) -> fp16
// ---------------------------------------------------------------------------
__global__ __launch_bounds__(256) void cvt_x(
    const float* __restrict__ x, f16* __restrict__ o)
{
  const size_t idx = ((size_t)blockIdx.x * 256 + threadIdx.x) * 4;
  const float4 v = *(const float4*)(x + idx);
  f16x4 h;
  h[0] = (f16)v.x; h[1] = (f16)v.y; h[2] = (f16)v.z; h[3] = (f16)v.w;
  *(f16x4*)(o + idx) = h;
}

// ---------------------------------------------------------------------------
// GEMM v2: out[t][o] = sum_k A[t][k]*W[o][k] + bias (+epilogue).
// EPI 0: relu->f16   EPI 1: +resid->f16   EPI 2: +resid->f32
// BM=BN=256, BK=32; K-tiles NT=32; 4 LDS buffers (A 16KB + B 16KB each).
// Pipeline ledger:
//   issue order strictly K-tile order, 4 VMEM instr/wave/K-tile.
//   iter t: outstanding {t,t+1,t+2}=12 -> vmcnt(8) retires tile t ->
//   barrier (all waves see t landed; all waves done reading buf[(t-1)&3]) ->
//   stage t+3 into buf[(t+3)&3]=buf[(t-1)&3] (safe) -> ds_read buf[t&3] -> MFMA.
//   tail: t=30 vmcnt(4), t=31 vmcnt(0).
// Swizzle (64B rows): phys_chunk = chunk ^ ((row>>1)&3); 16-lane frag reads
// cover the 8 (parity x chunk) bank slots 2x -> conflict-free.
// ---------------------------------------------------------------------------
template<int EPI>
__global__ __launch_bounds__(512, 2) void gemm2(
    const f16* __restrict__ A, const f16* __restrict__ W,
    const float* __restrict__ bias, const f16* __restrict__ resid,
    void* __restrict__ outp)
{
  __shared__ __align__(16) char smem[131072];   // 4 bufs x (A 16KB | B 16KB)

  // XCD swizzle: 256 blocks, 8 XCDs -> 32 consecutive per XCD (8 mt x 4 nt).
  const int orig = blockIdx.x;
  const int swzb = (orig & 7) * 32 + (orig >> 3);
  const int mt = swzb >> 2, nt = swzb & 3;
  const int t0 = mt * 256, n0 = nt * 256;

  const int tid  = threadIdx.x;
  const int lane = tid & 63;
  const int wid  = tid >> 6;
  const int wm = wid >> 2, wn = wid & 3;

  // staging: 512 thr x 16B = 8KB = one 128-row half of one operand.
  const int srow   = tid >> 2;                       // 0..127
  const int schunk = (tid & 3) ^ ((tid >> 3) & 3);   // inverse (= same) swizzle
  const f16* gA = A + (size_t)(t0 + srow) * DIM + schunk * 8;
  const f16* gB = W + (size_t)(n0 + srow) * DIM + schunk * 8;
  const int sdst = tid * 16;

  // fragment LDS byte offsets (kt-invariant; swizzle is row-dependent but
  // rows are base+lane&15 with 16-aligned base -> lane-only expression)
  const int kchunk = ((lane >> 4) ^ ((lane >> 1) & 3)) * 16;
  int aoff[8], boff[4];
  #pragma unroll
  for (int mi = 0; mi < 8; ++mi)
    aoff[mi] = (wm * 128 + mi * 16 + (lane & 15)) * 64 + kchunk;
  #pragma unroll
  for (int ni = 0; ni < 4; ++ni)
    boff[ni] = 16384 + (wn * 64 + ni * 16 + (lane & 15)) * 64 + kchunk;

  f32x4 acc[8][4] = {};

  auto stage = [&](int kt, int b) {
    const f16* as = gA + kt * 32;
    const f16* bs = gB + kt * 32;
    char* d = smem + b * 32768 + sdst;
    load_lds16(as, d);                              // A rows 0..127
    load_lds16(as + (size_t)128 * DIM, d + 8192);   // A rows 128..255
    load_lds16(bs, d + 16384);                      // B rows 0..127
    load_lds16(bs + (size_t)128 * DIM, d + 24576);  // B rows 128..255
  };
  auto body = [&](int b) {
    const char* base = smem + b * 32768;
    f16x8 af[8], bf[4];
    #pragma unroll
    for (int ni = 0; ni < 4; ++ni) bf[ni] = *(const f16x8*)(base + boff[ni]);
    #pragma unroll
    for (int mi = 0; mi < 8; ++mi) af[mi] = *(const f16x8*)(base + aoff[mi]);
    __builtin_amdgcn_s_setprio(1);
    #pragma unroll
    for (int mi = 0; mi < 8; ++mi)
      #pragma unroll
      for (int ni = 0; ni < 4; ++ni)
        acc[mi][ni] = __builtin_amdgcn_mfma_f32_16x16x32_f16(
            af[mi], bf[ni], acc[mi][ni], 0, 0, 0);
    __builtin_amdgcn_s_setprio(0);
  };

  stage(0, 0); stage(1, 1); stage(2, 2);

  for (int t = 0; t < 30; ++t) {
    asm volatile("s_waitcnt vmcnt(8)" ::: "memory");
    __builtin_amdgcn_s_barrier();
    __builtin_amdgcn_sched_barrier(0);
    if (t < 29) stage(t + 3, (t + 3) & 3);
    body(t & 3);
  }
  asm volatile("s_waitcnt vmcnt(4)" ::: "memory");
  __builtin_amdgcn_s_barrier();
  __builtin_amdgcn_sched_barrier(0);
  body(2);                                          // t=30
  asm volatile("s_waitcnt vmcnt(0)" ::: "memory");
  __builtin_amdgcn_s_barrier();
  __builtin_amdgcn_sched_barrier(0);
  body(3);                                          // t=31

  // epilogue: C/D col=lane&15, row=(lane>>4)*4+r
  const int colb = lane & 15;
  const int rowb = (lane >> 4) << 2;
  #pragma unroll
  for (int ni = 0; ni < 4; ++ni) {
    const int col = n0 + wn * 64 + ni * 16 + colb;
    const float bv = bias[col];
    #pragma unroll
    for (int mi = 0; mi < 8; ++mi) {
      const int trow = t0 + wm * 128 + mi * 16 + rowb;
      const f32x4 v = acc[mi][ni];
      #pragma unroll
      for (int r = 0; r < 4; ++r) {
        const size_t idx = (size_t)(trow + r) * DIM + col;
        float val = v[r] + bv;
        if constexpr (EPI == 0) {
          val = fmaxf(val, 0.f);
          ((f16*)outp)[idx] = (f16)val;
        } else if constexpr (EPI == 1) {
          val += (float)resid[idx];
          ((f16*)outp)[idx] = (f16)val;
        } else {
          val += (float)resid[idx];
          ((float*)outp)[idx] = val;
        }
      }
    }
  }
}

// ---------------------------------------------------------------------------
// LayerNorm over DIM=1024, one block per row, in-place safe.
// ---------------------------------------------------------------------------
__global__ __launch_bounds__(256) void ln_k(
    const f16* __restrict__ in, f16* __restrict__ out,
    const float* __restrict__ g, const float* __restrict__ b)
{
  __shared__ float red[8];
  const int row = blockIdx.x;
  const int tid = threadIdx.x;
  const int c = tid * 4;
  const f16x4 v4 = *(const f16x4*)(in + (size_t)row * DIM + c);
  const float v0 = v4[0], v1 = v4[1], v2 = v4[2], v3 = v4[3];
  float s  = v0 + v1 + v2 + v3;
  float s2 = v0 * v0 + v1 * v1 + v2 * v2 + v3 * v3;
  #pragma unroll
  for (int off = 32; off; off >>= 1) {
    s  += __shfl_xor(s,  off);
    s2 += __shfl_xor(s2, off);
  }
  if ((tid & 63) == 0) { red[(tid >> 6) * 2] = s; red[(tid >> 6) * 2 + 1] = s2; }
  __syncthreads();
  s  = red[0] + red[2] + red[4] + red[6];
  s2 = red[1] + red[3] + red[5] + red[7];
  const float mu  = s * (1.f / DIM);
  const float var = fmaxf(s2 * (1.f / DIM) - mu * mu, 0.f);
  const float rs  = rsqrtf(var + EPS);
  const float4 gv = *(const float4*)(g + c);
  const float4 bv = *(const float4*)(b + c);
  f16x4 o4;
  o4[0] = (f16)((v0 - mu) * rs * gv.x + bv.x);
  o4[1] = (f16)((v1 - mu) * rs * gv.y + bv.y);
  o4[2] = (f16)((v2 - mu) * rs * gv.z + bv.z);
  o4[3] = (f16)((v3 - mu) * rs * gv.w + bv.w);
  *(f16x4*)(out + (size_t)row * DIM + c) = o4;
}

// ---------------------------------------------------------------------------
extern "C" void kernel_launch(void* const* d_in, const int* in_sizes, int n_in,
                              void* d_out, int out_size, void* d_ws, size_t ws_size,
                              hipStream_t stream)
{
  (void)in_sizes; (void)n_in; (void)out_size; (void)ws_size;
  const float* x     = (const float*)d_in[0];
  const int*   q     = (const int*)d_in[1];
  const float* norm  = (const float*)d_in[2];
  const float* bias  = (const float*)d_in[3];
  const float* la    = (const float*)d_in[4];
  const float* lb    = (const float*)d_in[5];
  const float* lg    = (const float*)d_in[6];
  const float* lbeta = (const float*)d_in[7];

  char* ws = (char*)d_ws;
  f16* W    = (f16*)ws;                                   // 36 MB
  f16* buf1 = (f16*)(ws + (size_t)NLIN * DIM * DIM * 2);  // 32 MB
  f16* buf2 = buf1 + (size_t)TOK * DIM;                   // 32 MB
  f16* buf0 = (f16*)d_out;  // scratch inside the 64MB output; dead at final GEMM
  f16* bufs[3] = {buf0, buf1, buf2};

  prep_w2<<<NLIN * 32, 256, 0, stream>>>(q, norm, la, lb, W);
  cvt_x<<<TOK * DIM / 1024, 256, 0, stream>>>(x, buf0);

  int h = 0;
  for (int blk = 0; blk < 6; ++blk) {
    const int a = (h == 0) ? 1 : 0;
    const int p = 3 - h - a;
    const int i0 = blk * 3;
    const size_t wsz = (size_t)DIM * DIM;
    gemm2<0><<<256, 512, 0, stream>>>(bufs[h], W + (i0 + 0) * wsz,
                                      bias + (i0 + 0) * DIM, nullptr, bufs[a]);
    gemm2<0><<<256, 512, 0, stream>>>(bufs[a], W + (i0 + 1) * wsz,
                                      bias + (i0 + 1) * DIM, nullptr, bufs[p]);
    if (blk < 5) {
      gemm2<1><<<256, 512, 0, stream>>>(bufs[p], W + (i0 + 2) * wsz,
                                        bias + (i0 + 2) * DIM, bufs[h], bufs[a]);
      ln_k<<<TOK, 256, 0, stream>>>(bufs[a], bufs[a], lg + blk * DIM, lbeta + blk * DIM);
      h = a;
    } else {
      gemm2<2><<<256, 512, 0, stream>>>(bufs[p], W + (i0 + 2) * wsz,
                                        bias + (i0 + 2) * DIM, bufs[h], d_out);
    }
  }
}

// Round 5
// 1035.908 us; speedup vs baseline: 1.1310x; 1.0088x over previous
//
#include <hip/hip_runtime.h>
#include <stdint.h>

// QLoRA BigNet forward, MI355X/gfx950.  R5.
// prep_w2: validated (R4), unchanged.
// gemm3: m201-style 8-phase schedule. BM=BN=256, BK=64, 16 K-tiles, 8 waves
// (2Mx4N, 128x64 per wave), 2-slot LDS dbuf (128KB). 4 fine phases per K-tile:
// {ds_read subtile | issue gloads(t+1) | barrier | lgkmcnt(0) | setprio(1) |
// 16 MFMA | setprio(0) | barrier}. One vmcnt(0) per K-tile at ph3, after the
// t+1 loads have had ~2-3 phases of flight. Swizzle: chunk ^= (row&7) on 128B
// rows, applied on global source (linear gload dest) and on ds_read address.
// Ledger: tile t lands in slot t&1, confirmed by iter t-1 ph3 vmcnt(0)+BAR;
// slot o's prior readers finish (lgkmcnt(0)+BAR) before t+1's gloads issue.

#define TOK   16384
#define DIM   1024
#define NLIN  18
#define EPS   1e-5f

typedef _Float16 f16;
typedef _Float16 f16x8 __attribute__((ext_vector_type(8)));
typedef _Float16 f16x4 __attribute__((ext_vector_type(4)));
typedef float    f32x4 __attribute__((ext_vector_type(4)));

__device__ __forceinline__ void load_lds16(const void* g, void* l) {
  __builtin_amdgcn_global_load_lds(
      (const __attribute__((address_space(1))) void*)g,
      (__attribute__((address_space(3))) void*)l,
      16, 0, 0);
}

// ---------------------------------------------------------------------------
// prep v2 (validated R4): o-tiled lora fold, la in registers, lb in LDS.
// ---------------------------------------------------------------------------
__global__ __launch_bounds__(256) void prep_w2(
    const int* __restrict__ q, const float* __restrict__ norm,
    const float* __restrict__ la, const float* __restrict__ lb,
    f16* __restrict__ W)
{
  __shared__ float lbs[128 * 32];
  const int bid   = blockIdx.x;
  const int i     = bid >> 5;
  const int ot    = (bid >> 2) & 7;
  const int ktile = bid & 3;
  const int o0 = ot * 128, k0 = ktile * 256;
  const int tid = threadIdx.x;
  const int kg = tid & 63, og = tid >> 6;
  const int k4 = k0 + kg * 4;

  const float* lbsrc = lb + (size_t)i * DIM * 32 + (size_t)o0 * 32;
  #pragma unroll
  for (int p = 0; p < 4; ++p)
    *(float4*)(lbs + p * 1024 + tid * 4) = *(const float4*)(lbsrc + p * 1024 + tid * 4);

  float4 lar[32];
  const float* lasrc = la + (size_t)i * 32 * DIM + k4;
  #pragma unroll
  for (int r = 0; r < 32; ++r) lar[r] = *(const float4*)(lasrc + r * DIM);
  __syncthreads();

  const float s = 2.f / 15.f;
  for (int oi = 0; oi < 32; ++oi) {
    const int o = o0 + og * 32 + oi;
    const size_t wb = ((size_t)i * DIM + o) * DIM;
    const int4 qv = *(const int4*)(q + wb + k4);
    const float nrm = norm[((size_t)i * DIM + o) * 8 + (k4 >> 7)];
    const float* lbr = lbs + (og * 32 + oi) * 32;
    float ax = 0.f, ay = 0.f, az = 0.f, aw = 0.f;
    #pragma unroll
    for (int r = 0; r < 32; ++r) {
      const float b = lbr[r];
      ax += b * lar[r].x; ay += b * lar[r].y; az += b * lar[r].z; aw += b * lar[r].w;
    }
    f16x4 hv;
    hv[0] = (f16)(((float)qv.x * s - 1.f) * nrm + ax);
    hv[1] = (f16)(((float)qv.y * s - 1.f) * nrm + ay);
    hv[2] = (f16)(((float)qv.z * s - 1.f) * nrm + az);
    hv[3] = (f16)(((float)qv.w * s - 1.f) * nrm + aw);
    *(f16x4*)(W + wb + k4) = hv;
  }
}

// ---------------------------------------------------------------------------
__global__ __launch_bounds__(256) void cvt_x(
    const float* __restrict__ x, f16* __restrict__ o)
{
  const size_t idx = ((size_t)blockIdx.x * 256 + threadIdx.x) * 4;
  const float4 v = *(const float4*)(x + idx);
  f16x4 h;
  h[0] = (f16)v.x; h[1] = (f16)v.y; h[2] = (f16)v.z; h[3] = (f16)v.w;
  *(f16x4*)(o + idx) = h;
}

// ---------------------------------------------------------------------------
// gemm3: 8-phase schedule.  EPI 0: relu->f16  1: +resid->f16  2: +resid->f32
// ---------------------------------------------------------------------------
#define BARX()   __builtin_amdgcn_s_barrier()
#define LGKM0()  do { asm volatile("s_waitcnt lgkmcnt(0)" ::: "memory"); \
                      __builtin_amdgcn_sched_barrier(0); } while (0)
#define VMC0()   do { asm volatile("s_waitcnt vmcnt(0)" ::: "memory"); \
                      __builtin_amdgcn_sched_barrier(0); } while (0)

// af[0..7] <- A slot, K-half kk   (8 x ds_read_b128)
#define RD_AF(so, kk) do { \
  _Pragma("unroll") \
  for (int mi = 0; mi < 8; ++mi) \
    af[mi] = *(const f16x8*)(smem + (so) + arowb[mi] + (ckA ^ ((kk) << 6))); \
} while (0)

// bf[ni0], bf[ni0+1] <- B slot, K-half kk   (2 x ds_read_b128)
#define RD_BF(so, ni0, kk) do { \
  bf[ni0]     = *(const f16x8*)(smem + 65536 + (so) + browb[ni0]     + (ckA ^ ((kk) << 6))); \
  bf[(ni0)+1] = *(const f16x8*)(smem + 65536 + (so) + browb[(ni0)+1] + (ckA ^ ((kk) << 6))); \
} while (0)

// one C-quadrant x K=32: 16 MFMAs
#define QUAD(ni0) do { \
  __builtin_amdgcn_s_setprio(1); \
  _Pragma("unroll") \
  for (int mi = 0; mi < 8; ++mi) { \
    acc[mi][ni0]     = __builtin_amdgcn_mfma_f32_16x16x32_f16(af[mi], bf[ni0],     acc[mi][ni0],     0, 0, 0); \
    acc[mi][(ni0)+1] = __builtin_amdgcn_mfma_f32_16x16x32_f16(af[mi], bf[(ni0)+1], acc[mi][(ni0)+1], 0, 0, 0); \
  } \
  __builtin_amdgcn_s_setprio(0); \
} while (0)

// stage one 256x64 operand tile (4 x global_load_lds, 8KB each)
#define STAGE_A(kt, dstso) do { \
  _Pragma("unroll") \
  for (int qq = 0; qq < 4; ++qq) \
    load_lds16(gA + (size_t)(kt) * 64 + (size_t)qq * 64 * DIM, \
               smem + (dstso) + qq * 8192 + sdst); \
} while (0)
#define STAGE_B(kt, dstso) do { \
  _Pragma("unroll") \
  for (int qq = 0; qq < 4; ++qq) \
    load_lds16(gB + (size_t)(kt) * 64 + (size_t)qq * 64 * DIM, \
               smem + 65536 + (dstso) + qq * 8192 + sdst); \
} while (0)

template<int EPI>
__global__ __launch_bounds__(512, 2) void gemm3(
    const f16* __restrict__ A, const f16* __restrict__ W,
    const float* __restrict__ bias, const f16* __restrict__ resid,
    void* __restrict__ outp)
{
  // [A slot0 32K][A slot1 32K][B slot0 32K][B slot1 32K]
  __shared__ __align__(16) char smem[131072];

  // XCD swizzle: 256 blocks, 8 XCDs -> 32 consecutive per XCD (8 mt x 4 nt).
  const int orig = blockIdx.x;
  const int swzb = (orig & 7) * 32 + (orig >> 3);
  const int mt = swzb >> 2, nt = swzb & 3;
  const int t0 = mt * 256, n0 = nt * 256;

  const int tid  = threadIdx.x;
  const int lane = tid & 63;
  const int wid  = tid >> 6;
  const int wm = wid >> 2, wn = wid & 3;          // 2M x 4N waves

  // staging: 512 thr x 16B = 8KB = 64 rows x 8 chunks per gload instr.
  // LDS dest linear; source pre-swizzled: phys chunk p holds logical p^(row&7).
  const int srow = tid >> 3;                      // 0..63
  const int sch  = (tid & 7) ^ (srow & 7);
  const f16* gA = A + (size_t)(t0 + srow) * DIM + sch * 8;
  const f16* gB = W + (size_t)(n0 + srow) * DIM + sch * 8;
  const int sdst = tid * 16;

  // fragment read addressing: row ra -> byte ra*128 + ((chunk)^(ra&7))*16,
  // chunk = kk*4 + (lane>>4).  (ra&7)==(lane&7) since row bases are 16-mult.
  // ck(kk=1) = ck(kk=0) ^ 64  (since (x+4)^m == (x^m)^4 for x<4).
  const int ckA = (((lane >> 4) ^ (lane & 7)) << 4);
  int arowb[8], browb[4];
  #pragma unroll
  for (int mi = 0; mi < 8; ++mi)
    arowb[mi] = (wm * 128 + mi * 16 + (lane & 15)) * 128;
  #pragma unroll
  for (int ni = 0; ni < 4; ++ni)
    browb[ni] = (wn * 64 + ni * 16 + (lane & 15)) * 128;

  f32x4 acc[8][4] = {};
  f16x8 af[8], bf[4];

  // prologue: tile 0 -> slot 0
  STAGE_A(0, 0);
  STAGE_B(0, 0);
  VMC0();
  BARX();

  for (int t = 0; t < 16; ++t) {
    const int so = (t & 1) << 15;          // compute slot
    const int od = ((t + 1) & 1) << 15;    // prefetch slot
    const bool st = (t < 15);
    // ph0: af(kk0) + bf01(kk0) | stage A(t+1)
    RD_AF(so, 0); RD_BF(so, 0, 0);
    if (st) STAGE_A(t + 1, od);
    BARX(); LGKM0(); QUAD(0); BARX();
    // ph1: bf23(kk0) | stage B(t+1)
    RD_BF(so, 2, 0);
    if (st) STAGE_B(t + 1, od);
    BARX(); LGKM0(); QUAD(2); BARX();
    // ph2: af(kk1) + bf01(kk1)
    RD_AF(so, 1); RD_BF(so, 0, 1);
    BARX(); LGKM0(); QUAD(0); BARX();
    // ph3: bf23(kk1) | confirm tile t+1 landed (loads have 2-3 phases flight)
    RD_BF(so, 2, 1);
    VMC0();
    BARX(); LGKM0(); QUAD(2); BARX();
  }

  // epilogue: C/D col=lane&15, row=(lane>>4)*4+r
  const int colb = lane & 15;
  const int rowb = (lane >> 4) << 2;
  #pragma unroll
  for (int ni = 0; ni < 4; ++ni) {
    const int col = n0 + wn * 64 + ni * 16 + colb;
    const float bv = bias[col];
    #pragma unroll
    for (int mi = 0; mi < 8; ++mi) {
      const int trow = t0 + wm * 128 + mi * 16 + rowb;
      const f32x4 v = acc[mi][ni];
      #pragma unroll
      for (int r = 0; r < 4; ++r) {
        const size_t idx = (size_t)(trow + r) * DIM + col;
        float val = v[r] + bv;
        if constexpr (EPI == 0) {
          val = fmaxf(val, 0.f);
          ((f16*)outp)[idx] = (f16)val;
        } else if constexpr (EPI == 1) {
          val += (float)resid[idx];
          ((f16*)outp)[idx] = (f16)val;
        } else {
          val += (float)resid[idx];
          ((float*)outp)[idx] = val;
        }
      }
    }
  }
}

// ---------------------------------------------------------------------------
// LayerNorm over DIM=1024, one block per row, in-place safe.
// ---------------------------------------------------------------------------
__global__ __launch_bounds__(256) void ln_k(
    const f16* __restrict__ in, f16* __restrict__ out,
    const float* __restrict__ g, const float* __restrict__ b)
{
  __shared__ float red[8];
  const int row = blockIdx.x;
  const int tid = threadIdx.x;
  const int c = tid * 4;
  const f16x4 v4 = *(const f16x4*)(in + (size_t)row * DIM + c);
  const float v0 = v4[0], v1 = v4[1], v2 = v4[2], v3 = v4[3];
  float s  = v0 + v1 + v2 + v3;
  float s2 = v0 * v0 + v1 * v1 + v2 * v2 + v3 * v3;
  #pragma unroll
  for (int off = 32; off; off >>= 1) {
    s  += __shfl_xor(s,  off);
    s2 += __shfl_xor(s2, off);
  }
  if ((tid & 63) == 0) { red[(tid >> 6) * 2] = s; red[(tid >> 6) * 2 + 1] = s2; }
  __syncthreads();
  s  = red[0] + red[2] + red[4] + red[6];
  s2 = red[1] + red[3] + red[5] + red[7];
  const float mu  = s * (1.f / DIM);
  const float var = fmaxf(s2 * (1.f / DIM) - mu * mu, 0.f);
  const float rs  = rsqrtf(var + EPS);
  const float4 gv = *(const float4*)(g + c);
  const float4 bv = *(const float4*)(b + c);
  f16x4 o4;
  o4[0] = (f16)((v0 - mu) * rs * gv.x + bv.x);
  o4[1] = (f16)((v1 - mu) * rs * gv.y + bv.y);
  o4[2] = (f16)((v2 - mu) * rs * gv.z + bv.z);
  o4[3] = (f16)((v3 - mu) * rs * gv.w + bv.w);
  *(f16x4*)(out + (size_t)row * DIM + c) = o4;
}

// ---------------------------------------------------------------------------
extern "C" void kernel_launch(void* const* d_in, const int* in_sizes, int n_in,
                              void* d_out, int out_size, void* d_ws, size_t ws_size,
                              hipStream_t stream)
{
  (void)in_sizes; (void)n_in; (void)out_size; (void)ws_size;
  const float* x     = (const float*)d_in[0];
  const int*   q     = (const int*)d_in[1];
  const float* norm  = (const float*)d_in[2];
  const float* bias  = (const float*)d_in[3];
  const float* la    = (const float*)d_in[4];
  const float* lb    = (const float*)d_in[5];
  const float* lg    = (const float*)d_in[6];
  const float* lbeta = (const float*)d_in[7];

  char* ws = (char*)d_ws;
  f16* W    = (f16*)ws;                                   // 36 MB
  f16* buf1 = (f16*)(ws + (size_t)NLIN * DIM * DIM * 2);  // 32 MB
  f16* buf2 = buf1 + (size_t)TOK * DIM;                   // 32 MB
  f16* buf0 = (f16*)d_out;  // scratch inside the 64MB output; dead at final GEMM
  f16* bufs[3] = {buf0, buf1, buf2};

  prep_w2<<<NLIN * 32, 256, 0, stream>>>(q, norm, la, lb, W);
  cvt_x<<<TOK * DIM / 1024, 256, 0, stream>>>(x, buf0);

  int h = 0;
  for (int blk = 0; blk < 6; ++blk) {
    const int a = (h == 0) ? 1 : 0;
    const int p = 3 - h - a;
    const int i0 = blk * 3;
    const size_t wsz = (size_t)DIM * DIM;
    gemm3<0><<<256, 512, 0, stream>>>(bufs[h], W + (i0 + 0) * wsz,
                                      bias + (i0 + 0) * DIM, nullptr, bufs[a]);
    gemm3<0><<<256, 512, 0, stream>>>(bufs[a], W + (i0 + 1) * wsz,
                                      bias + (i0 + 1) * DIM, nullptr, bufs[p]);
    if (blk < 5) {
      gemm3<1><<<256, 512, 0, stream>>>(bufs[p], W + (i0 + 2) * wsz,
                                        bias + (i0 + 2) * DIM, bufs[h], bufs[a]);
      ln_k<<<TOK, 256, 0, stream>>>(bufs[a], bufs[a], lg + blk * DIM, lbeta + blk * DIM);
      h = a;
    } else {
      gemm3<2><<<256, 512, 0, stream>>>(bufs[p], W + (i0 + 2) * wsz,
                                        bias + (i0 + 2) * DIM, bufs[h], d_out);
    }
  }
}

// Round 6
// 981.561 us; speedup vs baseline: 1.1936x; 1.0554x over previous
//
#include <hip/hip_runtime.h>
#include <stdint.h>

// QLoRA BigNet forward, MI355X/gfx950.  R6.
// gemm4: the untested winning cell {8-phase fine interleave + COUNTED vmcnt}.
// 256x256, BK=64, 8 waves (2Mx4N), 2-slot LDS dbuf (2x64KB).
// Per K-tile: 4 phases, each {ds_reads for NEXT phase's MFMA | 2 gloads |
// [ph3: vmcnt(2)] | s_barrier | setprio(1) 16 MFMA setprio(0)}.
// Staging: pieces (16KB, 2 gloads): Bh0(t+1)@ph0, Bh1(t+1)@ph1,
// Ah0(t+2)@ph2, Ah1(t+2)@ph3.  vmcnt(2)@ph3 retires all of tile t+1 (FIFO)
// while Ah0/Ah1(t+2) remain in flight -> never drains (tail t>=14 drains).
// lgkm waits: compiler-managed (near-optimal per m97); barriers pin phases.
// Swizzle: chunk ^= (row&7) on 128B rows, both-sides (pre-swizzled global
// source + XOR'd ds_read address); bank-conflict measured 0 in R4/R5.

#define TOK   16384
#define DIM   1024
#define NLIN  18
#define EPS   1e-5f

typedef _Float16 f16;
typedef _Float16 f16x8 __attribute__((ext_vector_type(8)));
typedef _Float16 f16x4 __attribute__((ext_vector_type(4)));
typedef float    f32x4 __attribute__((ext_vector_type(4)));

__device__ __forceinline__ void load_lds16(const void* g, void* l) {
  __builtin_amdgcn_global_load_lds(
      (const __attribute__((address_space(1))) void*)g,
      (__attribute__((address_space(3))) void*)l,
      16, 0, 0);
}

// ---------------------------------------------------------------------------
// prep v2 (validated R4): o-tiled lora fold, la in registers, lb in LDS.
// ---------------------------------------------------------------------------
__global__ __launch_bounds__(256) void prep_w2(
    const int* __restrict__ q, const float* __restrict__ norm,
    const float* __restrict__ la, const float* __restrict__ lb,
    f16* __restrict__ W)
{
  __shared__ float lbs[128 * 32];
  const int bid   = blockIdx.x;
  const int i     = bid >> 5;
  const int ot    = (bid >> 2) & 7;
  const int ktile = bid & 3;
  const int o0 = ot * 128, k0 = ktile * 256;
  const int tid = threadIdx.x;
  const int kg = tid & 63, og = tid >> 6;
  const int k4 = k0 + kg * 4;

  const float* lbsrc = lb + (size_t)i * DIM * 32 + (size_t)o0 * 32;
  #pragma unroll
  for (int p = 0; p < 4; ++p)
    *(float4*)(lbs + p * 1024 + tid * 4) = *(const float4*)(lbsrc + p * 1024 + tid * 4);

  float4 lar[32];
  const float* lasrc = la + (size_t)i * 32 * DIM + k4;
  #pragma unroll
  for (int r = 0; r < 32; ++r) lar[r] = *(const float4*)(lasrc + r * DIM);
  __syncthreads();

  const float s = 2.f / 15.f;
  for (int oi = 0; oi < 32; ++oi) {
    const int o = o0 + og * 32 + oi;
    const size_t wb = ((size_t)i * DIM + o) * DIM;
    const int4 qv = *(const int4*)(q + wb + k4);
    const float nrm = norm[((size_t)i * DIM + o) * 8 + (k4 >> 7)];
    const float* lbr = lbs + (og * 32 + oi) * 32;
    float ax = 0.f, ay = 0.f, az = 0.f, aw = 0.f;
    #pragma unroll
    for (int r = 0; r < 32; ++r) {
      const float b = lbr[r];
      ax += b * lar[r].x; ay += b * lar[r].y; az += b * lar[r].z; aw += b * lar[r].w;
    }
    f16x4 hv;
    hv[0] = (f16)(((float)qv.x * s - 1.f) * nrm + ax);
    hv[1] = (f16)(((float)qv.y * s - 1.f) * nrm + ay);
    hv[2] = (f16)(((float)qv.z * s - 1.f) * nrm + az);
    hv[3] = (f16)(((float)qv.w * s - 1.f) * nrm + aw);
    *(f16x4*)(W + wb + k4) = hv;
  }
}

// ---------------------------------------------------------------------------
__global__ __launch_bounds__(256) void cvt_x(
    const float* __restrict__ x, f16* __restrict__ o)
{
  const size_t idx = ((size_t)blockIdx.x * 256 + threadIdx.x) * 4;
  const float4 v = *(const float4*)(x + idx);
  f16x4 h;
  h[0] = (f16)v.x; h[1] = (f16)v.y; h[2] = (f16)v.z; h[3] = (f16)v.w;
  *(f16x4*)(o + idx) = h;
}

// ---------------------------------------------------------------------------
// gemm4.  EPI 0: relu->f16  1: +resid->f16  2: +resid->f32
// LDS slot (64KB): [Ah0 16K][Ah1 16K][Bh0 16K][Bh1 16K]; 2 slots = 128KB.
// ---------------------------------------------------------------------------
#define BARX() __builtin_amdgcn_s_barrier()

// afd[0..7] <- slot sl, K-half kk (8 x ds_read_b128)
#define RD_AF(afd, sl, kk) do { \
  _Pragma("unroll") \
  for (int mi = 0; mi < 8; ++mi) \
    afd[mi] = *(const f16x8*)(smem + (sl) + wmbase + arowb[mi] + (ckA ^ ((kk) << 6))); \
} while (0)

// b0,b1 <- slot sl, n-pair np, K-half kk (2 x ds_read_b128)
#define RD_BF(b0, b1, sl, np, kk) do { \
  b0 = *(const f16x8*)(smem + (sl) + 32768 + wnhalf + browb[(np)*2]     + (ckA ^ ((kk) << 6))); \
  b1 = *(const f16x8*)(smem + (sl) + 32768 + wnhalf + browb[(np)*2 + 1] + (ckA ^ ((kk) << 6))); \
} while (0)

// one C-quadrant: 16 MFMAs into acc[.][nn], acc[.][nn+1]
#define QUAD(afr, b0, b1, nn) do { \
  __builtin_amdgcn_s_setprio(1); \
  _Pragma("unroll") \
  for (int mi = 0; mi < 8; ++mi) { \
    acc[mi][nn]     = __builtin_amdgcn_mfma_f32_16x16x32_f16(afr[mi], b0, acc[mi][nn],     0, 0, 0); \
    acc[mi][(nn)+1] = __builtin_amdgcn_mfma_f32_16x16x32_f16(afr[mi], b1, acc[mi][(nn)+1], 0, 0, 0); \
  } \
  __builtin_amdgcn_s_setprio(0); \
} while (0)

// stage one A half-piece (2 gloads, 16KB): rows h*128..h*128+127, k-tile T
#define STAGE_A(T, h, dslot) do { \
  load_lds16(gA + (size_t)((T) * 64) + (size_t)((h) * 128) * DIM, \
             smem + (dslot) + (h) * 16384 + sdst); \
  load_lds16(gA + (size_t)((T) * 64) + (size_t)((h) * 128 + 64) * DIM, \
             smem + (dslot) + (h) * 16384 + 8192 + sdst); \
} while (0)
#define STAGE_B(T, h, dslot) do { \
  load_lds16(gB + (size_t)((T) * 64) + (size_t)((h) * 128) * DIM, \
             smem + (dslot) + 32768 + (h) * 16384 + sdst); \
  load_lds16(gB + (size_t)((T) * 64) + (size_t)((h) * 128 + 64) * DIM, \
             smem + (dslot) + 32768 + (h) * 16384 + 8192 + sdst); \
} while (0)

template<int EPI>
__global__ __launch_bounds__(512, 2) void gemm4(
    const f16* __restrict__ A, const f16* __restrict__ W,
    const float* __restrict__ bias, const f16* __restrict__ resid,
    void* __restrict__ outp)
{
  __shared__ __align__(16) char smem[131072];

  // XCD swizzle: 256 blocks, 8 XCDs -> 32 consecutive per XCD (8 mt x 4 nt).
  const int orig = blockIdx.x;
  const int swzb = (orig & 7) * 32 + (orig >> 3);
  const int mt = swzb >> 2, nt = swzb & 3;
  const int t0 = mt * 256, n0 = nt * 256;

  const int tid  = threadIdx.x;
  const int lane = tid & 63;
  const int wid  = tid >> 6;
  const int wm = wid >> 2, wn = wid & 3;          // 2M x 4N waves

  // staging: 512 thr x 16B = 8KB = 64 rows x 8 chunks per gload.
  // LDS dest linear; global source pre-swizzled (chunk ^= row&7).
  const int srow = tid >> 3;                      // 0..63
  const int sch  = (tid & 7) ^ (srow & 7);
  const f16* gA = A + (size_t)(t0 + srow) * DIM + sch * 8;
  const f16* gB = W + (size_t)(n0 + srow) * DIM + sch * 8;
  const int sdst = tid * 16;

  // fragment addressing (row bases 16-aligned -> row&7 == lane&7)
  const int ckA    = (((lane >> 4) ^ (lane & 7)) << 4);
  const int wmbase = wm * 16384;
  const int wnhalf = (wn >> 1) * 16384;
  int arowb[8], browb[4];
  #pragma unroll
  for (int mi = 0; mi < 8; ++mi)
    arowb[mi] = (mi * 16 + (lane & 15)) * 128;
  #pragma unroll
  for (int ni = 0; ni < 4; ++ni)
    browb[ni] = ((wn & 1) * 64 + ni * 16 + (lane & 15)) * 128;

  f32x4 acc[8][4] = {};
  f16x8 afX[8], afY[8];
  f16x8 bfP0, bfP1, bfQ0, bfQ1, bfP20, bfP21, bfQ20, bfQ21;

  // prologue: tile0 all 4 pieces -> slot0; A pieces of tile1 -> slot1.
  STAGE_A(0, 0, 0); STAGE_A(0, 1, 0);
  STAGE_B(0, 0, 0); STAGE_B(0, 1, 0);
  STAGE_A(1, 0, 65536); STAGE_A(1, 1, 65536);
  asm volatile("s_waitcnt vmcnt(4)" ::: "memory");   // tile0 landed; A(1) in flight
  BARX();
  RD_AF(afX, 0, 0);
  RD_BF(bfP0, bfP1, 0, 0, 0);

  for (int t = 0; t < 16; ++t) {
    const int sl = (t & 1) << 16;
    const int ns = sl ^ 65536;
    // ph0: reads for ph1 | stage Bh0(t+1)
    RD_BF(bfQ0, bfQ1, sl, 1, 0);
    if (t < 15) STAGE_B(t + 1, 0, ns);
    BARX();
    QUAD(afX, bfP0, bfP1, 0);
    // ph1: reads for ph2 | stage Bh1(t+1)
    RD_AF(afY, sl, 1);
    RD_BF(bfP20, bfP21, sl, 0, 1);
    if (t < 15) STAGE_B(t + 1, 1, ns);
    BARX();
    QUAD(afX, bfQ0, bfQ1, 2);
    // ph2: reads for ph3 | stage Ah0(t+2)
    RD_BF(bfQ20, bfQ21, sl, 1, 1);
    if (t < 14) STAGE_A(t + 2, 0, sl);
    BARX();
    QUAD(afY, bfP20, bfP21, 0);
    // ph3: stage Ah1(t+2) | counted vmcnt retires tile t+1 | reads for ph0(t+1)
    if (t < 14) {
      STAGE_A(t + 2, 1, sl);
      asm volatile("s_waitcnt vmcnt(2)" ::: "memory");
    } else {
      asm volatile("s_waitcnt vmcnt(0)" ::: "memory");
    }
    BARX();
    if (t < 15) {
      RD_AF(afX, ns, 0);
      RD_BF(bfP0, bfP1, ns, 0, 0);
    }
    QUAD(afY, bfQ20, bfQ21, 2);
  }

  // epilogue: C/D col=lane&15, row=(lane>>4)*4+r
  const int colb = lane & 15;
  const int rowb = (lane >> 4) << 2;
  #pragma unroll
  for (int ni = 0; ni < 4; ++ni) {
    const int col = n0 + wn * 64 + ni * 16 + colb;
    const float bv = bias[col];
    #pragma unroll
    for (int mi = 0; mi < 8; ++mi) {
      const int trow = t0 + wm * 128 + mi * 16 + rowb;
      const f32x4 v = acc[mi][ni];
      #pragma unroll
      for (int r = 0; r < 4; ++r) {
        const size_t idx = (size_t)(trow + r) * DIM + col;
        float val = v[r] + bv;
        if constexpr (EPI == 0) {
          val = fmaxf(val, 0.f);
          ((f16*)outp)[idx] = (f16)val;
        } else if constexpr (EPI == 1) {
          val += (float)resid[idx];
          ((f16*)outp)[idx] = (f16)val;
        } else {
          val += (float)resid[idx];
          ((float*)outp)[idx] = val;
        }
      }
    }
  }
}

// ---------------------------------------------------------------------------
// LayerNorm over DIM=1024, one block per row, in-place safe.
// ---------------------------------------------------------------------------
__global__ __launch_bounds__(256) void ln_k(
    const f16* __restrict__ in, f16* __restrict__ out,
    const float* __restrict__ g, const float* __restrict__ b)
{
  __shared__ float red[8];
  const int row = blockIdx.x;
  const int tid = threadIdx.x;
  const int c = tid * 4;
  const f16x4 v4 = *(const f16x4*)(in + (size_t)row * DIM + c);
  const float v0 = v4[0], v1 = v4[1], v2 = v4[2], v3 = v4[3];
  float s  = v0 + v1 + v2 + v3;
  float s2 = v0 * v0 + v1 * v1 + v2 * v2 + v3 * v3;
  #pragma unroll
  for (int off = 32; off; off >>= 1) {
    s  += __shfl_xor(s,  off);
    s2 += __shfl_xor(s2, off);
  }
  if ((tid & 63) == 0) { red[(tid >> 6) * 2] = s; red[(tid >> 6) * 2 + 1] = s2; }
  __syncthreads();
  s  = red[0] + red[2] + red[4] + red[6];
  s2 = red[1] + red[3] + red[5] + red[7];
  const float mu  = s * (1.f / DIM);
  const float var = fmaxf(s2 * (1.f / DIM) - mu * mu, 0.f);
  const float rs  = rsqrtf(var + EPS);
  const float4 gv = *(const float4*)(g + c);
  const float4 bv = *(const float4*)(b + c);
  f16x4 o4;
  o4[0] = (f16)((v0 - mu) * rs * gv.x + bv.x);
  o4[1] = (f16)((v1 - mu) * rs * gv.y + bv.y);
  o4[2] = (f16)((v2 - mu) * rs * gv.z + bv.z);
  o4[3] = (f16)((v3 - mu) * rs * gv.w + bv.w);
  *(f16x4*)(out + (size_t)row * DIM + c) = o4;
}

// ---------------------------------------------------------------------------
extern "C" void kernel_launch(void* const* d_in, const int* in_sizes, int n_in,
                              void* d_out, int out_size, void* d_ws, size_t ws_size,
                              hipStream_t stream)
{
  (void)in_sizes; (void)n_in; (void)out_size; (void)ws_size;
  const float* x     = (const float*)d_in[0];
  const int*   q     = (const int*)d_in[1];
  const float* norm  = (const float*)d_in[2];
  const float* bias  = (const float*)d_in[3];
  const float* la    = (const float*)d_in[4];
  const float* lb    = (const float*)d_in[5];
  const float* lg    = (const float*)d_in[6];
  const float* lbeta = (const float*)d_in[7];

  char* ws = (char*)d_ws;
  f16* W    = (f16*)ws;                                   // 36 MB
  f16* buf1 = (f16*)(ws + (size_t)NLIN * DIM * DIM * 2);  // 32 MB
  f16* buf2 = buf1 + (size_t)TOK * DIM;                   // 32 MB
  f16* buf0 = (f16*)d_out;  // scratch inside the 64MB output; dead at final GEMM
  f16* bufs[3] = {buf0, buf1, buf2};

  prep_w2<<<NLIN * 32, 256, 0, stream>>>(q, norm, la, lb, W);
  cvt_x<<<TOK * DIM / 1024, 256, 0, stream>>>(x, buf0);

  int h = 0;
  for (int blk = 0; blk < 6; ++blk) {
    const int a = (h == 0) ? 1 : 0;
    const int p = 3 - h - a;
    const int i0 = blk * 3;
    const size_t wsz = (size_t)DIM * DIM;
    gemm4<0><<<256, 512, 0, stream>>>(bufs[h], W + (i0 + 0) * wsz,
                                      bias + (i0 + 0) * DIM, nullptr, bufs[a]);
    gemm4<0><<<256, 512, 0, stream>>>(bufs[a], W + (i0 + 1) * wsz,
                                      bias + (i0 + 1) * DIM, nullptr, bufs[p]);
    if (blk < 5) {
      gemm4<1><<<256, 512, 0, stream>>>(bufs[p], W + (i0 + 2) * wsz,
                                        bias + (i0 + 2) * DIM, bufs[h], bufs[a]);
      ln_k<<<TOK, 256, 0, stream>>>(bufs[a], bufs[a], lg + blk * DIM, lbeta + blk * DIM);
      h = a;
    } else {
      gemm4<2><<<256, 512, 0, stream>>>(bufs[p], W + (i0 + 2) * wsz,
                                        bias + (i0 + 2) * DIM, bufs[h], d_out);
    }
  }
}